// Round 1
// baseline (1763.556 us; speedup 1.0000x reference)
//
#include <hip/hip_runtime.h>
#include <math.h>

// ---------------------------------------------------------------------------
// MinkowskiNet-style sparse CNN forward, fp32 baseline.
// Stages: mlp1 -> 5x(conv+down+pool) -> conv6 -> segpool -> f1 -> f2 -> f3
// Each BN block: producer writes raw; stats kernel accumulates sum/sumsq;
// apply kernel normalizes + LeakyReLU in place (scale/shift recomputed per
// element from raw sums -- cheap, avoids a finalize kernel).
// ---------------------------------------------------------------------------

#define SLOPE 0.01f
#define BN_EPS 1e-5f

__global__ void zero_kernel(float* __restrict__ p, int n) {
    int i = blockIdx.x * blockDim.x + threadIdx.x;
    if (i < n) p[i] = 0.f;
}

// out[n,co] = sum_ci in[n,ci] * w[ci,co]   (generic, runtime dims)
__global__ void lin_kernel(const float* __restrict__ in, const float* __restrict__ w,
                           float* __restrict__ out, int total, int Cin, int Cout) {
    int stride = gridDim.x * blockDim.x;
    for (int i = blockIdx.x * blockDim.x + threadIdx.x; i < total; i += stride) {
        int n = i / Cout;
        int co = i - n * Cout;
        const float* row = in + n * Cin;
        float acc = 0.f;
        for (int ci = 0; ci < Cin; ci++)
            acc = fmaf(row[ci], w[ci * Cout + co], acc);
        out[i] = acc;
    }
}

// per-channel sum & sumsq.  Host guarantees blockDim % C == 0, so each
// thread's channel is constant across its grid-stride walk -> register acc.
__global__ void stats_kernel(const float* __restrict__ x, int total, int C,
                             float* __restrict__ sums) {
    __shared__ float ls[1024];
    int tid = threadIdx.x;
    for (int i = tid; i < 2 * C; i += blockDim.x) ls[i] = 0.f;
    __syncthreads();
    int stride = gridDim.x * blockDim.x;
    int i = blockIdx.x * blockDim.x + tid;
    int c = i % C;
    float s = 0.f, q = 0.f;
    for (; i < total; i += stride) {
        float v = x[i];
        s += v;
        q = fmaf(v, v, q);
    }
    atomicAdd(&ls[c], s);
    atomicAdd(&ls[C + c], q);
    __syncthreads();
    for (int j = tid; j < 2 * C; j += blockDim.x)
        atomicAdd(&sums[j], ls[j]);
}

// x = lrelu( (x - mean) * g * rsqrt(var+eps) + b ), stats from raw sums
__global__ void bn_apply_kernel(float* __restrict__ x, int total, int C,
                                const float* __restrict__ sums,
                                const float* __restrict__ g, const float* __restrict__ b,
                                float inv_n) {
    int stride = gridDim.x * blockDim.x;
    for (int i = blockIdx.x * blockDim.x + threadIdx.x; i < total; i += stride) {
        int c = i % C;
        float mean = sums[c] * inv_n;
        float var = fmaf(-mean, mean, sums[C + c] * inv_n);
        var = fmaxf(var, 0.f);
        float scale = g[c] * rsqrtf(var + BN_EPS);
        float v = fmaf(x[i] - mean, scale, b[c]);
        x[i] = v >= 0.f ? v : SLOPE * v;
    }
}

// out[n,c] = max_k in[pmap[n,k], c]
__global__ void maxpool_kernel(const float* __restrict__ in, const int* __restrict__ pmap,
                               float* __restrict__ out, int total, int C) {
    int stride = gridDim.x * blockDim.x;
    for (int i = blockIdx.x * blockDim.x + threadIdx.x; i < total; i += stride) {
        int n = i / C;
        int c = i - n * C;
        const int* pm = pmap + n * 27;
        float m = -INFINITY;
        #pragma unroll
        for (int k = 0; k < 27; k++)
            m = fmaxf(m, in[pm[k] * C + c]);
        out[i] = m;
    }
}

// concat(in1,in2) @ w : out[n,co] = sum in1[n,:]*w[0:C1] + in2[n,:]*w[C1:C1+C2]
template <int C1, int C2, int COUT>
__global__ void down_kernel(const float* __restrict__ in1, const float* __restrict__ in2,
                            const float* __restrict__ w, float* __restrict__ out, int total) {
    int stride = gridDim.x * blockDim.x;
    for (int i = blockIdx.x * blockDim.x + threadIdx.x; i < total; i += stride) {
        int n = i / COUT;
        int co = i - n * COUT;
        float acc = 0.f;
        const float4* r1 = reinterpret_cast<const float4*>(in1 + n * C1);
        #pragma unroll
        for (int j = 0; j < C1 / 4; j++) {
            float4 a = r1[j];
            int ci = j * 4;
            acc = fmaf(a.x, w[(ci + 0) * COUT + co], acc);
            acc = fmaf(a.y, w[(ci + 1) * COUT + co], acc);
            acc = fmaf(a.z, w[(ci + 2) * COUT + co], acc);
            acc = fmaf(a.w, w[(ci + 3) * COUT + co], acc);
        }
        const float4* r2 = reinterpret_cast<const float4*>(in2 + n * C2);
        #pragma unroll
        for (int j = 0; j < C2 / 4; j++) {
            float4 a = r2[j];
            int ci = C1 + j * 4;
            acc = fmaf(a.x, w[(ci + 0) * COUT + co], acc);
            acc = fmaf(a.y, w[(ci + 1) * COUT + co], acc);
            acc = fmaf(a.z, w[(ci + 2) * COUT + co], acc);
            acc = fmaf(a.w, w[(ci + 3) * COUT + co], acc);
        }
        out[i] = acc;
    }
}

// gather-GEMM sparse conv: out[n,co] = sum_k sum_ci y[nbr[n,k],ci] * w[k,ci,co]
// Block: COUT*MW threads; TM rows staged in LDS; each thread owns RT=TM/MW rows.
template <int CIN, int COUT, int TM, int MW>
__global__ __launch_bounds__(COUT * MW) void conv_kernel(
    const float* __restrict__ y, const int* __restrict__ nbr,
    const float* __restrict__ w, float* __restrict__ out, int N) {
    constexpr int RT = TM / MW;
    constexpr int AER = 27 * CIN;  // gathered elems per output row
    __shared__ __align__(16) float a[TM * AER];
    const int tid = threadIdx.x;
    const int nthr = COUT * MW;
    const int m0 = blockIdx.x * TM;

    for (int idx = tid; idx < TM * AER; idx += nthr) {
        int m = idx / AER;
        int rem = idx - m * AER;
        int k = rem / CIN;
        int ci = rem - k * CIN;
        int row = nbr[(m0 + m) * 27 + k];
        a[idx] = y[row * CIN + ci];
    }
    __syncthreads();

    const int co = tid % COUT;
    const int mg = tid / COUT;
    float acc[RT];
    #pragma unroll
    for (int r = 0; r < RT; r++) acc[r] = 0.f;

    for (int k = 0; k < 27; k++) {
        #pragma unroll
        for (int ci = 0; ci < CIN; ci += 4) {
            const float* wp = &w[(k * CIN + ci) * COUT + co];
            float w0 = wp[0];
            float w1 = wp[COUT];
            float w2 = wp[2 * COUT];
            float w3 = wp[3 * COUT];
            #pragma unroll
            for (int r = 0; r < RT; r++) {
                const float4 av = *reinterpret_cast<const float4*>(
                    &a[(mg + r * MW) * AER + k * CIN + ci]);
                acc[r] = fmaf(av.x, w0, acc[r]);
                acc[r] = fmaf(av.y, w1, acc[r]);
                acc[r] = fmaf(av.z, w2, acc[r]);
                acc[r] = fmaf(av.w, w3, acc[r]);
            }
        }
    }
    #pragma unroll
    for (int r = 0; r < RT; r++)
        out[(m0 + mg + r * MW) * COUT + co] = acc[r];
}

// y[256,512] -> z[8,1024]: per contiguous 32-row segment, max || mean
__global__ void segpool_kernel(const float* __restrict__ y, float* __restrict__ z) {
    int b = blockIdx.x;
    int c = threadIdx.x;  // 512 threads
    float mx = -INFINITY, sm = 0.f;
    for (int r = 0; r < 32; r++) {
        float v = y[(b * 32 + r) * 512 + c];
        mx = fmaxf(mx, v);
        sm += v;
    }
    z[b * 1024 + c] = mx;
    z[b * 1024 + 512 + c] = sm * (1.f / 32.f);
}

// final: out[8,20] = in[8,256] @ w[256,20] + bias
__global__ void f3_kernel(const float* __restrict__ in, const float* __restrict__ w,
                          const float* __restrict__ bias, float* __restrict__ out) {
    int i = blockIdx.x * blockDim.x + threadIdx.x;
    if (i >= 160) return;
    int n = i / 20;
    int co = i - n * 20;
    float acc = bias[co];
    for (int ci = 0; ci < 256; ci++)
        acc = fmaf(in[n * 256 + ci], w[ci * 20 + co], acc);
    out[i] = acc;
}

// ---------------------------------------------------------------------------

static inline int stats_block(int C) {
    if (C == 48 || C == 96) return 192;
    if (C == 512) return 512;
    return 256;
}
static inline int capgrid(int total, int block) {
    int g = (total + block - 1) / block;
    return g > 4096 ? 4096 : g;
}

extern "C" void kernel_launch(void* const* d_in, const int* in_sizes, int n_in,
                              void* d_out, int out_size, void* d_ws, size_t ws_size,
                              hipStream_t stream) {
    (void)in_sizes; (void)n_in; (void)out_size; (void)ws_size;

    const int N0 = 131072, N1 = 32768, N2 = 8192, N3 = 2048, N4 = 512, N5 = 256;

    const float* x      = (const float*)d_in[0];
    const float* w_mlp1 = (const float*)d_in[1];
    const float* g_mlp1 = (const float*)d_in[2];
    const float* b_mlp1 = (const float*)d_in[3];
    const float* w_c[6]; const float* g_c[6]; const float* b_c[6];
    for (int i = 0; i < 6; i++) {
        w_c[i] = (const float*)d_in[4 + 3 * i];
        g_c[i] = (const float*)d_in[5 + 3 * i];
        b_c[i] = (const float*)d_in[6 + 3 * i];
    }
    const float* w_d[5]; const float* g_d[5]; const float* b_d[5];
    for (int i = 0; i < 5; i++) {
        w_d[i] = (const float*)d_in[22 + 3 * i];
        g_d[i] = (const float*)d_in[23 + 3 * i];
        b_d[i] = (const float*)d_in[24 + 3 * i];
    }
    const float* w_f1 = (const float*)d_in[37];
    const float* g_f1 = (const float*)d_in[38];
    const float* b_f1 = (const float*)d_in[39];
    const float* w_f2 = (const float*)d_in[40];
    const float* g_f2 = (const float*)d_in[41];
    const float* b_f2 = (const float*)d_in[42];
    const float* w_f3 = (const float*)d_in[43];
    const float* bias_f3 = (const float*)d_in[44];
    const int* nbr[6];
    for (int i = 0; i < 6; i++) nbr[i] = (const int*)d_in[45 + i];
    const int* pool[5];
    for (int i = 0; i < 5; i++) pool[i] = (const int*)d_in[51 + i];

    float* ws    = (float*)d_ws;
    float* bufA  = ws;                    // 2,097,152 floats (y buffers)
    float* bufB  = bufA + 2097152;        // 4,194,304 floats (conv outs)
    float* bufC  = bufB + 4194304;        // 4,194,304 floats (down outs / z)
    float* stats = bufC + 4194304;        // 14 * 1024 floats
    const int NSTAT = 14 * 1024;

    float* out = (float*)d_out;

    // helper lambdas (host side)
    auto run_stats = [&](float* buf, int total, int C, int slot) {
        int bs = stats_block(C);
        int gr = capgrid(total, bs);
        if (gr > 256) gr = 256;
        stats_kernel<<<gr, bs, 0, stream>>>(buf, total, C, stats + slot * 1024);
    };
    auto run_apply = [&](float* buf, int total, int C, int slot,
                         const float* g, const float* b, float inv_n) {
        bn_apply_kernel<<<capgrid(total, 256), 256, 0, stream>>>(
            buf, total, C, stats + slot * 1024, g, b, inv_n);
    };

    zero_kernel<<<(NSTAT + 255) / 256, 256, 0, stream>>>(stats, NSTAT);

    // ---- mlp1: [N0,3] @ [3,16], BN, lrelu -> bufA [N0,16]
    lin_kernel<<<capgrid(N0 * 16, 256), 256, 0, stream>>>(x, w_mlp1, bufA, N0 * 16, 3, 16);
    run_stats(bufA, N0 * 16, 16, 0);
    run_apply(bufA, N0 * 16, 16, 0, g_mlp1, b_mlp1, 1.f / N0);

    // ---- level 0: conv1 16->32, down1 48->32, pool1
    conv_kernel<16, 32, 32, 8><<<N0 / 32, 256, 0, stream>>>(bufA, nbr[0], w_c[0], bufB, N0);
    run_stats(bufB, N0 * 32, 32, 1);
    run_apply(bufB, N0 * 32, 32, 1, g_c[0], b_c[0], 1.f / N0);
    down_kernel<16, 32, 32><<<capgrid(N0 * 32, 256), 256, 0, stream>>>(bufA, bufB, w_d[0], bufC, N0 * 32);
    run_stats(bufC, N0 * 32, 32, 2);
    run_apply(bufC, N0 * 32, 32, 2, g_d[0], b_d[0], 1.f / N0);
    maxpool_kernel<<<capgrid(N1 * 32, 256), 256, 0, stream>>>(bufC, pool[0], bufA, N1 * 32, 32);

    // ---- level 1: conv2 32->48, down2 80->48, pool2
    conv_kernel<32, 48, 16, 4><<<N1 / 16, 192, 0, stream>>>(bufA, nbr[1], w_c[1], bufB, N1);
    run_stats(bufB, N1 * 48, 48, 3);
    run_apply(bufB, N1 * 48, 48, 3, g_c[1], b_c[1], 1.f / N1);
    down_kernel<32, 48, 48><<<capgrid(N1 * 48, 256), 256, 0, stream>>>(bufA, bufB, w_d[1], bufC, N1 * 48);
    run_stats(bufC, N1 * 48, 48, 4);
    run_apply(bufC, N1 * 48, 48, 4, g_d[1], b_d[1], 1.f / N1);
    maxpool_kernel<<<capgrid(N2 * 48, 256), 256, 0, stream>>>(bufC, pool[1], bufA, N2 * 48, 48);

    // ---- level 2: conv3 48->96, down3 144->96, pool3
    conv_kernel<48, 96, 8, 2><<<N2 / 8, 192, 0, stream>>>(bufA, nbr[2], w_c[2], bufB, N2);
    run_stats(bufB, N2 * 96, 96, 5);
    run_apply(bufB, N2 * 96, 96, 5, g_c[2], b_c[2], 1.f / N2);
    down_kernel<48, 96, 96><<<capgrid(N2 * 96, 256), 256, 0, stream>>>(bufA, bufB, w_d[2], bufC, N2 * 96);
    run_stats(bufC, N2 * 96, 96, 6);
    run_apply(bufC, N2 * 96, 96, 6, g_d[2], b_d[2], 1.f / N2);
    maxpool_kernel<<<capgrid(N3 * 96, 256), 256, 0, stream>>>(bufC, pool[2], bufA, N3 * 96, 96);

    // ---- level 3: conv4 96->128, down4 224->128, pool4
    conv_kernel<96, 128, 4, 2><<<N3 / 4, 256, 0, stream>>>(bufA, nbr[3], w_c[3], bufB, N3);
    run_stats(bufB, N3 * 128, 128, 7);
    run_apply(bufB, N3 * 128, 128, 7, g_c[3], b_c[3], 1.f / N3);
    down_kernel<96, 128, 128><<<capgrid(N3 * 128, 256), 256, 0, stream>>>(bufA, bufB, w_d[3], bufC, N3 * 128);
    run_stats(bufC, N3 * 128, 128, 8);
    run_apply(bufC, N3 * 128, 128, 8, g_d[3], b_d[3], 1.f / N3);
    maxpool_kernel<<<capgrid(N4 * 128, 256), 256, 0, stream>>>(bufC, pool[3], bufA, N4 * 128, 128);

    // ---- level 4: conv5 128->256, down5 384->256, pool5
    conv_kernel<128, 256, 4, 1><<<N4 / 4, 256, 0, stream>>>(bufA, nbr[4], w_c[4], bufB, N4);
    run_stats(bufB, N4 * 256, 256, 9);
    run_apply(bufB, N4 * 256, 256, 9, g_c[4], b_c[4], 1.f / N4);
    down_kernel<128, 256, 256><<<capgrid(N4 * 256, 256), 256, 0, stream>>>(bufA, bufB, w_d[4], bufC, N4 * 256);
    run_stats(bufC, N4 * 256, 256, 10);
    run_apply(bufC, N4 * 256, 256, 10, g_d[4], b_d[4], 1.f / N4);
    maxpool_kernel<<<capgrid(N5 * 256, 256), 256, 0, stream>>>(bufC, pool[4], bufA, N5 * 256, 256);

    // ---- level 5: conv6 256->512
    conv_kernel<256, 512, 2, 1><<<N5 / 2, 512, 0, stream>>>(bufA, nbr[5], w_c[5], bufB, N5);
    run_stats(bufB, N5 * 512, 512, 11);
    run_apply(bufB, N5 * 512, 512, 11, g_c[5], b_c[5], 1.f / N5);

    // ---- segment max+avg pooling -> z in bufC [8,1024]
    segpool_kernel<<<8, 512, 0, stream>>>(bufB, bufC);

    // ---- f1: [8,1024]@[1024,512], BN over 8 rows, lrelu
    lin_kernel<<<capgrid(8 * 512, 256), 256, 0, stream>>>(bufC, w_f1, bufA, 8 * 512, 1024, 512);
    run_stats(bufA, 8 * 512, 512, 12);
    run_apply(bufA, 8 * 512, 512, 12, g_f1, b_f1, 1.f / 8.f);

    // ---- f2: [8,512]@[512,256]
    lin_kernel<<<capgrid(8 * 256, 256), 256, 0, stream>>>(bufA, w_f2, bufB, 8 * 256, 512, 256);
    run_stats(bufB, 8 * 256, 256, 13);
    run_apply(bufB, 8 * 256, 256, 13, g_f2, b_f2, 1.f / 8.f);

    // ---- f3: [8,256]@[256,20] + bias -> d_out
    f3_kernel<<<1, 192, 0, stream>>>(bufB, w_f3, bias_f3, out);
}

// Round 2
// 1076.626 us; speedup vs baseline: 1.6380x; 1.6380x over previous
//
#include <hip/hip_runtime.h>
#include <math.h>

// ---------------------------------------------------------------------------
// MinkowskiNet-style sparse CNN forward, fp32, round 2.
//  - conv: m-tile x co-tile x k-split grid, per-k LDS gather, co-quad threads
//  - down: co-quad threads, float4 weight loads
//  - fc:   co-major coalesced, 16-way in-block K-split + 4-way grid K-split
// BN: producer writes raw -> stats kernel -> apply kernel (unchanged).
// ---------------------------------------------------------------------------

#define SLOPE 0.01f
#define BN_EPS 1e-5f

__device__ __forceinline__ void fma4(float s, const float4& w, float4& a) {
    a.x = fmaf(s, w.x, a.x);
    a.y = fmaf(s, w.y, a.y);
    a.z = fmaf(s, w.z, a.z);
    a.w = fmaf(s, w.w, a.w);
}

__global__ void zero_kernel(float* __restrict__ p, int n) {
    int i = blockIdx.x * blockDim.x + threadIdx.x;
    if (i < n) p[i] = 0.f;
}

// generic small-K linear (used for mlp1 only: Cin=3)
__global__ void lin_kernel(const float* __restrict__ in, const float* __restrict__ w,
                           float* __restrict__ out, int total, int Cin, int Cout) {
    int stride = gridDim.x * blockDim.x;
    for (int i = blockIdx.x * blockDim.x + threadIdx.x; i < total; i += stride) {
        int n = i / Cout;
        int co = i - n * Cout;
        const float* row = in + n * Cin;
        float acc = 0.f;
        for (int ci = 0; ci < Cin; ci++)
            acc = fmaf(row[ci], w[ci * Cout + co], acc);
        out[i] = acc;
    }
}

// per-channel sum & sumsq.  Host guarantees blockDim % C == 0.
__global__ void stats_kernel(const float* __restrict__ x, int total, int C,
                             float* __restrict__ sums) {
    __shared__ float ls[1024];
    int tid = threadIdx.x;
    for (int i = tid; i < 2 * C; i += blockDim.x) ls[i] = 0.f;
    __syncthreads();
    int stride = gridDim.x * blockDim.x;
    int i = blockIdx.x * blockDim.x + tid;
    int c = i % C;
    float s = 0.f, q = 0.f;
    for (; i < total; i += stride) {
        float v = x[i];
        s += v;
        q = fmaf(v, v, q);
    }
    atomicAdd(&ls[c], s);
    atomicAdd(&ls[C + c], q);
    __syncthreads();
    for (int j = tid; j < 2 * C; j += blockDim.x)
        atomicAdd(&sums[j], ls[j]);
}

__global__ void bn_apply_kernel(float* __restrict__ x, int total, int C,
                                const float* __restrict__ sums,
                                const float* __restrict__ g, const float* __restrict__ b,
                                float inv_n) {
    int stride = gridDim.x * blockDim.x;
    for (int i = blockIdx.x * blockDim.x + threadIdx.x; i < total; i += stride) {
        int c = i % C;
        float mean = sums[c] * inv_n;
        float var = fmaf(-mean, mean, sums[C + c] * inv_n);
        var = fmaxf(var, 0.f);
        float scale = g[c] * rsqrtf(var + BN_EPS);
        float v = fmaf(x[i] - mean, scale, b[c]);
        x[i] = v >= 0.f ? v : SLOPE * v;
    }
}

__global__ void maxpool_kernel(const float* __restrict__ in, const int* __restrict__ pmap,
                               float* __restrict__ out, int total, int C) {
    int stride = gridDim.x * blockDim.x;
    for (int i = blockIdx.x * blockDim.x + threadIdx.x; i < total; i += stride) {
        int n = i / C;
        int c = i - n * C;
        const int* pm = pmap + n * 27;
        float m = -INFINITY;
        #pragma unroll
        for (int k = 0; k < 27; k++)
            m = fmaxf(m, in[pm[k] * C + c]);
        out[i] = m;
    }
}

// down (concat + 1x1): each thread computes one co-quad of one row.
template <int C1, int C2, int COUT>
__global__ void down2_kernel(const float* __restrict__ in1, const float* __restrict__ in2,
                             const float* __restrict__ w, float* __restrict__ out, int Nrows) {
    constexpr int CQT = COUT / 4;
    int i = blockIdx.x * blockDim.x + threadIdx.x;
    if (i >= Nrows * CQT) return;
    int n = i / CQT;
    int coq = i - n * CQT;
    const float4* w4 = reinterpret_cast<const float4*>(w);
    float4 acc = make_float4(0.f, 0.f, 0.f, 0.f);
    const float4* r1 = reinterpret_cast<const float4*>(in1 + n * C1);
    #pragma unroll
    for (int j = 0; j < C1 / 4; j++) {
        float4 a = r1[j];
        fma4(a.x, w4[(4 * j + 0) * CQT + coq], acc);
        fma4(a.y, w4[(4 * j + 1) * CQT + coq], acc);
        fma4(a.z, w4[(4 * j + 2) * CQT + coq], acc);
        fma4(a.w, w4[(4 * j + 3) * CQT + coq], acc);
    }
    const float4* r2 = reinterpret_cast<const float4*>(in2 + n * C2);
    #pragma unroll
    for (int j = 0; j < C2 / 4; j++) {
        float4 a = r2[j];
        int ci = C1 + 4 * j;
        fma4(a.x, w4[(ci + 0) * CQT + coq], acc);
        fma4(a.y, w4[(ci + 1) * CQT + coq], acc);
        fma4(a.z, w4[(ci + 2) * CQT + coq], acc);
        fma4(a.w, w4[(ci + 3) * CQT + coq], acc);
    }
    reinterpret_cast<float4*>(out)[i] = acc;
}

// sparse conv: grid (N/TM, COUT/CO_TILE, 27/KT).  Per k-offset: gather TM rows
// into LDS, stream w as float4 (co-quad per thread), FMA.  ATOMIC for k-split.
template <int CIN, int COUT, int TM, int CO_TILE, int KT, int NTHR, bool ATOMIC>
__global__ __launch_bounds__(NTHR) void conv2_kernel(
    const float* __restrict__ y, const int* __restrict__ nbr,
    const float* __restrict__ w, float* __restrict__ out) {
    constexpr int CQ = CO_TILE / 4;   // co-quads per tile
    constexpr int MGRP = NTHR / CQ;   // distinct thread m-groups
    constexpr int RT = TM / MGRP;     // rows per thread
    constexpr int LROW = CIN + 4;     // padded LDS row (floats)
    __shared__ __align__(16) float a[TM * LROW];

    const int m0 = blockIdx.x * TM;
    const int cobase = blockIdx.y * CO_TILE;
    const int k0 = blockIdx.z * KT;
    const int tid = threadIdx.x;
    const int coq = tid % CQ;
    const int mg = tid / CQ;

    float4 acc[RT];
    #pragma unroll
    for (int r = 0; r < RT; r++) acc[r] = make_float4(0.f, 0.f, 0.f, 0.f);

    for (int k = k0; k < k0 + KT; k++) {
        __syncthreads();  // previous iteration's reads done
        for (int idx = tid; idx < TM * (CIN / 4); idx += NTHR) {
            int m = idx / (CIN / 4);
            int c4 = idx - m * (CIN / 4);
            int row = nbr[(m0 + m) * 27 + k];
            float4 v = *reinterpret_cast<const float4*>(y + row * CIN + c4 * 4);
            *reinterpret_cast<float4*>(&a[m * LROW + c4 * 4]) = v;
        }
        __syncthreads();
        const float* wk = w + k * CIN * COUT + cobase + coq * 4;
        #pragma unroll
        for (int ci = 0; ci < CIN; ci += 4) {
            float4 w0 = *reinterpret_cast<const float4*>(wk + (ci + 0) * COUT);
            float4 w1 = *reinterpret_cast<const float4*>(wk + (ci + 1) * COUT);
            float4 w2 = *reinterpret_cast<const float4*>(wk + (ci + 2) * COUT);
            float4 w3 = *reinterpret_cast<const float4*>(wk + (ci + 3) * COUT);
            #pragma unroll
            for (int r = 0; r < RT; r++) {
                const float4 av = *reinterpret_cast<const float4*>(
                    &a[(mg + r * MGRP) * LROW + ci]);
                fma4(av.x, w0, acc[r]);
                fma4(av.y, w1, acc[r]);
                fma4(av.z, w2, acc[r]);
                fma4(av.w, w3, acc[r]);
            }
        }
    }
    #pragma unroll
    for (int r = 0; r < RT; r++) {
        float* op = out + (size_t)(m0 + mg + r * MGRP) * COUT + cobase + coq * 4;
        if (ATOMIC) {
            atomicAdd(op + 0, acc[r].x);
            atomicAdd(op + 1, acc[r].y);
            atomicAdd(op + 2, acc[r].z);
            atomicAdd(op + 3, acc[r].w);
        } else {
            *reinterpret_cast<float4*>(op) = acc[r];
        }
    }
}

// y[256,512] -> z[8,1024]
__global__ void segpool_kernel(const float* __restrict__ y, float* __restrict__ z) {
    int b = blockIdx.x;
    int c = threadIdx.x;
    float mx = -INFINITY, sm = 0.f;
    for (int r = 0; r < 32; r++) {
        float v = y[(b * 32 + r) * 512 + c];
        mx = fmaxf(mx, v);
        sm += v;
    }
    z[b * 1024 + c] = mx;
    z[b * 1024 + 512 + c] = sm * (1.f / 32.f);
}

// FC (M=8): grid (COUT/64, KSPLIT).  256 thr = 16 co-quads x 16 k-groups.
template <int K, int COUT, int KSPLIT>
__global__ __launch_bounds__(256) void fc_kernel(const float* __restrict__ z,
                                                 const float* __restrict__ w,
                                                 float* __restrict__ out) {
    constexpr int KC = K / KSPLIT;  // K per block
    constexpr int KG = KC / 16;     // K per thread
    __shared__ __align__(16) float zt[KC * 8];  // [k][n] transposed slice
    __shared__ float red[16 * 520];             // [kg][co_local*8+n], padded

    const int cobase = blockIdx.x * 64;
    const int kc0 = blockIdx.y * KC;
    const int tid = threadIdx.x;
    const int coq = tid & 15;
    const int kg = tid >> 4;

    for (int idx = tid; idx < 8 * (KC / 4); idx += 256) {
        int n = idx / (KC / 4);
        int kq = idx - n * (KC / 4);
        float4 v = *reinterpret_cast<const float4*>(z + n * K + kc0 + kq * 4);
        zt[(kq * 4 + 0) * 8 + n] = v.x;
        zt[(kq * 4 + 1) * 8 + n] = v.y;
        zt[(kq * 4 + 2) * 8 + n] = v.z;
        zt[(kq * 4 + 3) * 8 + n] = v.w;
    }
    __syncthreads();

    float4 acc[8];
    #pragma unroll
    for (int n = 0; n < 8; n++) acc[n] = make_float4(0.f, 0.f, 0.f, 0.f);
    for (int ki = 0; ki < KG; ki++) {
        int k = kg * KG + ki;
        float4 wv = *reinterpret_cast<const float4*>(
            w + (size_t)(kc0 + k) * COUT + cobase + coq * 4);
        float4 za = *reinterpret_cast<const float4*>(&zt[k * 8]);
        float4 zb = *reinterpret_cast<const float4*>(&zt[k * 8 + 4]);
        fma4(za.x, wv, acc[0]);
        fma4(za.y, wv, acc[1]);
        fma4(za.z, wv, acc[2]);
        fma4(za.w, wv, acc[3]);
        fma4(zb.x, wv, acc[4]);
        fma4(zb.y, wv, acc[5]);
        fma4(zb.z, wv, acc[6]);
        fma4(zb.w, wv, acc[7]);
    }
    #pragma unroll
    for (int n = 0; n < 8; n++) {
        red[kg * 520 + (coq * 4 + 0) * 8 + n] = acc[n].x;
        red[kg * 520 + (coq * 4 + 1) * 8 + n] = acc[n].y;
        red[kg * 520 + (coq * 4 + 2) * 8 + n] = acc[n].z;
        red[kg * 520 + (coq * 4 + 3) * 8 + n] = acc[n].w;
    }
    __syncthreads();
    for (int oi = tid; oi < 512; oi += 256) {
        int c = oi >> 3;
        int n = oi & 7;
        float s = 0.f;
        #pragma unroll
        for (int g = 0; g < 16; g++) s += red[g * 520 + c * 8 + n];
        float* op = out + n * COUT + cobase + c;
        if (KSPLIT > 1) atomicAdd(op, s);
        else *op = s;
    }
}

__global__ void f3_kernel(const float* __restrict__ in, const float* __restrict__ w,
                          const float* __restrict__ bias, float* __restrict__ out) {
    int i = blockIdx.x * blockDim.x + threadIdx.x;
    if (i >= 160) return;
    int n = i / 20;
    int co = i - n * 20;
    float acc = bias[co];
    for (int ci = 0; ci < 256; ci++)
        acc = fmaf(in[n * 256 + ci], w[ci * 20 + co], acc);
    out[i] = acc;
}

// ---------------------------------------------------------------------------

static inline int stats_block(int C) {
    if (C == 48 || C == 96) return 192;
    if (C == 512) return 512;
    return 256;
}
static inline int capgrid(int total, int block) {
    int g = (total + block - 1) / block;
    return g > 4096 ? 4096 : g;
}

extern "C" void kernel_launch(void* const* d_in, const int* in_sizes, int n_in,
                              void* d_out, int out_size, void* d_ws, size_t ws_size,
                              hipStream_t stream) {
    (void)in_sizes; (void)n_in; (void)out_size; (void)ws_size;

    const int N0 = 131072, N1 = 32768, N2 = 8192, N3 = 2048, N4 = 512, N5 = 256;

    const float* x      = (const float*)d_in[0];
    const float* w_mlp1 = (const float*)d_in[1];
    const float* g_mlp1 = (const float*)d_in[2];
    const float* b_mlp1 = (const float*)d_in[3];
    const float* w_c[6]; const float* g_c[6]; const float* b_c[6];
    for (int i = 0; i < 6; i++) {
        w_c[i] = (const float*)d_in[4 + 3 * i];
        g_c[i] = (const float*)d_in[5 + 3 * i];
        b_c[i] = (const float*)d_in[6 + 3 * i];
    }
    const float* w_d[5]; const float* g_d[5]; const float* b_d[5];
    for (int i = 0; i < 5; i++) {
        w_d[i] = (const float*)d_in[22 + 3 * i];
        g_d[i] = (const float*)d_in[23 + 3 * i];
        b_d[i] = (const float*)d_in[24 + 3 * i];
    }
    const float* w_f1 = (const float*)d_in[37];
    const float* g_f1 = (const float*)d_in[38];
    const float* b_f1 = (const float*)d_in[39];
    const float* w_f2 = (const float*)d_in[40];
    const float* g_f2 = (const float*)d_in[41];
    const float* b_f2 = (const float*)d_in[42];
    const float* w_f3 = (const float*)d_in[43];
    const float* bias_f3 = (const float*)d_in[44];
    const int* nbr[6];
    for (int i = 0; i < 6; i++) nbr[i] = (const int*)d_in[45 + i];
    const int* pool[5];
    for (int i = 0; i < 5; i++) pool[i] = (const int*)d_in[51 + i];

    float* ws    = (float*)d_ws;
    float* bufA  = ws;
    float* bufB  = bufA + 2097152;
    float* bufC  = bufB + 4194304;
    float* stats = bufC + 4194304;
    const int NSTAT = 14 * 1024;
    float* out = (float*)d_out;

    auto run_stats = [&](float* buf, int total, int C, int slot) {
        int bs = stats_block(C);
        int gr = capgrid(total, bs);
        if (gr > 256) gr = 256;
        stats_kernel<<<gr, bs, 0, stream>>>(buf, total, C, stats + slot * 1024);
    };
    auto run_apply = [&](float* buf, int total, int C, int slot,
                         const float* g, const float* b, float inv_n) {
        bn_apply_kernel<<<capgrid(total, 256), 256, 0, stream>>>(
            buf, total, C, stats + slot * 1024, g, b, inv_n);
    };

    zero_kernel<<<(NSTAT + 255) / 256, 256, 0, stream>>>(stats, NSTAT);

    // ---- mlp1
    lin_kernel<<<capgrid(N0 * 16, 256), 256, 0, stream>>>(x, w_mlp1, bufA, N0 * 16, 3, 16);
    run_stats(bufA, N0 * 16, 16, 0);
    run_apply(bufA, N0 * 16, 16, 0, g_mlp1, b_mlp1, 1.f / N0);

    // ---- level 0: conv1 16->32, down1 48->32, pool1
    conv2_kernel<16, 32, 32, 32, 27, 256, false>
        <<<dim3(N0 / 32, 1, 1), 256, 0, stream>>>(bufA, nbr[0], w_c[0], bufB);
    run_stats(bufB, N0 * 32, 32, 1);
    run_apply(bufB, N0 * 32, 32, 1, g_c[0], b_c[0], 1.f / N0);
    down2_kernel<16, 32, 32><<<capgrid(N0 * 8, 256), 256, 0, stream>>>(bufA, bufB, w_d[0], bufC, N0);
    run_stats(bufC, N0 * 32, 32, 2);
    run_apply(bufC, N0 * 32, 32, 2, g_d[0], b_d[0], 1.f / N0);
    maxpool_kernel<<<capgrid(N1 * 32, 256), 256, 0, stream>>>(bufC, pool[0], bufA, N1 * 32, 32);

    // ---- level 1: conv2 32->48, down2 80->48, pool2
    conv2_kernel<32, 48, 32, 48, 27, 192, false>
        <<<dim3(N1 / 32, 1, 1), 192, 0, stream>>>(bufA, nbr[1], w_c[1], bufB);
    run_stats(bufB, N1 * 48, 48, 3);
    run_apply(bufB, N1 * 48, 48, 3, g_c[1], b_c[1], 1.f / N1);
    down2_kernel<32, 48, 48><<<capgrid(N1 * 12, 256), 256, 0, stream>>>(bufA, bufB, w_d[1], bufC, N1);
    run_stats(bufC, N1 * 48, 48, 4);
    run_apply(bufC, N1 * 48, 48, 4, g_d[1], b_d[1], 1.f / N1);
    maxpool_kernel<<<capgrid(N2 * 48, 256), 256, 0, stream>>>(bufC, pool[1], bufA, N2 * 48, 48);

    // ---- level 2: conv3 48->96, down3 144->96, pool3
    conv2_kernel<48, 96, 16, 48, 27, 192, false>
        <<<dim3(N2 / 16, 2, 1), 192, 0, stream>>>(bufA, nbr[2], w_c[2], bufB);
    run_stats(bufB, N2 * 96, 96, 5);
    run_apply(bufB, N2 * 96, 96, 5, g_c[2], b_c[2], 1.f / N2);
    down2_kernel<48, 96, 96><<<capgrid(N2 * 24, 256), 256, 0, stream>>>(bufA, bufB, w_d[2], bufC, N2);
    run_stats(bufC, N2 * 96, 96, 6);
    run_apply(bufC, N2 * 96, 96, 6, g_d[2], b_d[2], 1.f / N2);
    maxpool_kernel<<<capgrid(N3 * 96, 256), 256, 0, stream>>>(bufC, pool[2], bufA, N3 * 96, 96);

    // ---- level 3: conv4 96->128 (k-split), down4 224->128, pool4
    zero_kernel<<<(N3 * 128 + 255) / 256, 256, 0, stream>>>(bufB, N3 * 128);
    conv2_kernel<96, 128, 16, 64, 9, 256, true>
        <<<dim3(N3 / 16, 2, 3), 256, 0, stream>>>(bufA, nbr[3], w_c[3], bufB);
    run_stats(bufB, N3 * 128, 128, 7);
    run_apply(bufB, N3 * 128, 128, 7, g_c[3], b_c[3], 1.f / N3);
    down2_kernel<96, 128, 128><<<capgrid(N3 * 32, 256), 256, 0, stream>>>(bufA, bufB, w_d[3], bufC, N3);
    run_stats(bufC, N3 * 128, 128, 8);
    run_apply(bufC, N3 * 128, 128, 8, g_d[3], b_d[3], 1.f / N3);
    maxpool_kernel<<<capgrid(N4 * 128, 256), 256, 0, stream>>>(bufC, pool[3], bufA, N4 * 128, 128);

    // ---- level 4: conv5 128->256 (k-split), down5 384->256, pool5
    zero_kernel<<<(N4 * 256 + 255) / 256, 256, 0, stream>>>(bufB, N4 * 256);
    conv2_kernel<128, 256, 8, 64, 9, 128, true>
        <<<dim3(N4 / 8, 4, 3), 128, 0, stream>>>(bufA, nbr[4], w_c[4], bufB);
    run_stats(bufB, N4 * 256, 256, 9);
    run_apply(bufB, N4 * 256, 256, 9, g_c[4], b_c[4], 1.f / N4);
    down2_kernel<128, 256, 256><<<capgrid(N4 * 64, 256), 256, 0, stream>>>(bufA, bufB, w_d[4], bufC, N4);
    run_stats(bufC, N4 * 256, 256, 10);
    run_apply(bufC, N4 * 256, 256, 10, g_d[4], b_d[4], 1.f / N4);
    maxpool_kernel<<<capgrid(N5 * 256, 256), 256, 0, stream>>>(bufC, pool[4], bufA, N5 * 256, 256);

    // ---- level 5: conv6 256->512 (k-split)
    zero_kernel<<<(N5 * 512 + 255) / 256, 256, 0, stream>>>(bufB, N5 * 512);
    conv2_kernel<256, 512, 8, 64, 9, 128, true>
        <<<dim3(N5 / 8, 8, 3), 128, 0, stream>>>(bufA, nbr[5], w_c[5], bufB);
    run_stats(bufB, N5 * 512, 512, 11);
    run_apply(bufB, N5 * 512, 512, 11, g_c[5], b_c[5], 1.f / N5);

    // ---- segment pooling -> bufC [8,1024]
    segpool_kernel<<<8, 512, 0, stream>>>(bufB, bufC);

    // ---- f1: [8,1024]@[1024,512]
    zero_kernel<<<(4096 + 255) / 256, 256, 0, stream>>>(bufA, 4096);
    fc_kernel<1024, 512, 4><<<dim3(8, 4), 256, 0, stream>>>(bufC, w_f1, bufA);
    run_stats(bufA, 8 * 512, 512, 12);
    run_apply(bufA, 8 * 512, 512, 12, g_f1, b_f1, 1.f / 8.f);

    // ---- f2: [8,512]@[512,256]
    zero_kernel<<<(2048 + 255) / 256, 256, 0, stream>>>(bufB, 2048);
    fc_kernel<512, 256, 4><<<dim3(4, 4), 256, 0, stream>>>(bufA, w_f2, bufB);
    run_stats(bufB, 8 * 256, 256, 13);
    run_apply(bufB, 8 * 256, 256, 13, g_f2, b_f2, 1.f / 8.f);

    // ---- f3
    f3_kernel<<<1, 192, 0, stream>>>(bufB, w_f3, bias_f3, out);
}